// Round 6
// baseline (116.223 us; speedup 1.0000x reference)
//
#include <hip/hip_runtime.h>
#include <math.h>

#define NPROP 1000
#define NCLS  81
#define KCOMP 11
#define DETS  100
#define CAP   96      // per-class valid cap (mean ~29, +12 sigma)
#define MAXK  3072    // global candidate cap (expect ~1500)
#define RMAXR 256     // refine-set cap (expect ~120)

// Single-workgroup megakernel: 1024 threads, 16 waves, one CU.
// No kernel boundaries, no device-scope fences - all via LDS + __syncthreads.
__global__ __launch_bounds__(1024) void fused_kernel(
    const float* __restrict__ cls_logits,
    const float* __restrict__ comp_logits,
    const float* __restrict__ boxreg,
    const float* __restrict__ props,
    float* __restrict__ ws,     // [MAXK] float4 candidate boxes
    float* __restrict__ out, int out_size)
{
    __shared__ int            ccnt[84];            // per-class valid count (idx c)
    __shared__ float          cscore[80][CAP];     // unordered (score)
    __shared__ unsigned short cnn[80][CAP];        // unordered (n)
    __shared__ float          comp_s[NPROP];
    __shared__ unsigned char  comp_i[NPROP];
    __shared__ float          sS[16][CAP];         // per-wave sorted scores
    __shared__ unsigned short sN[16][CAP];         // per-wave sorted n
    __shared__ float4         wbox[16][CAP];       // per-wave decoded boxes
    __shared__ unsigned long long candKey[MAXK];
    __shared__ int            hist[512];
    __shared__ unsigned long long rkey[RMAXR];
    __shared__ int            ridx[RMAXR];
    __shared__ int            candCnt, rcnt;

    int tid  = threadIdx.x;
    int lane = tid & 63;
    int wave = tid >> 6;

    if (tid < out_size) out[tid] = (tid >= 400 && tid < 500) ? -1.0f : 0.0f;
    if (tid < 84) ccnt[tid] = 0;
    if (tid == 0) { candCnt = 0; rcnt = 0; }
    __syncthreads();

    // ================= Phase AB: row softmax + valid append + comp stats ====
    // 16-lane groups; group G handles row n = iter*64 + G. Coalesced row loads.
    {
        int q = tid & 15;
        int G = tid >> 4;   // 0..63
        for (int iter = 0; iter < 16; ++iter) {
            int n = iter * 64 + G;
            if (n >= NPROP) break;                 // group-uniform, no syncs inside
            const float* row = &cls_logits[n * NCLS];
            float v0 = row[q];
            float v1 = row[q + 16];
            float v2 = row[q + 32];
            float v3 = row[q + 48];
            float v4 = row[q + 64];
            float v5 = (q == 0) ? row[80] : -INFINITY;
            float cv = (q < KCOMP) ? comp_logits[n * KCOMP + q] : -INFINITY;

            float m = fmaxf(fmaxf(fmaxf(v0, v1), fmaxf(v2, v3)), fmaxf(v4, v5));
            m = fmaxf(m, __shfl_xor(m, 1));
            m = fmaxf(m, __shfl_xor(m, 2));
            m = fmaxf(m, __shfl_xor(m, 4));
            m = fmaxf(m, __shfl_xor(m, 8));
            float e0 = expf(v0 - m), e1 = expf(v1 - m), e2 = expf(v2 - m),
                  e3 = expf(v3 - m), e4 = expf(v4 - m);
            float e5 = (q == 0) ? expf(v5 - m) : 0.0f;
            float s = e0 + e1 + e2 + e3 + e4 + e5;
            s += __shfl_xor(s, 1); s += __shfl_xor(s, 2);
            s += __shfl_xor(s, 4); s += __shfl_xor(s, 8);

            float pr[6] = {e0 / s, e1 / s, e2 / s, e3 / s, e4 / s, e5 / s};
#pragma unroll
            for (int j = 0; j < 5; ++j) {
                int c = q + 16 * j;
                if (c >= 1 && pr[j] > 0.05f) {
                    int pos = atomicAdd(&ccnt[c], 1);
                    if (pos < CAP) { cscore[c - 1][pos] = pr[j];
                                     cnn[c - 1][pos] = (unsigned short)n; }
                }
            }
            if (q == 0 && pr[5] > 0.05f) {
                int pos = atomicAdd(&ccnt[80], 1);
                if (pos < CAP) { cscore[79][pos] = pr[5];
                                 cnn[79][pos] = (unsigned short)n; }
            }

            // component softmax + fg max/argmax (first occurrence)
            float mc = cv;
            mc = fmaxf(mc, __shfl_xor(mc, 1));
            mc = fmaxf(mc, __shfl_xor(mc, 2));
            mc = fmaxf(mc, __shfl_xor(mc, 4));
            mc = fmaxf(mc, __shfl_xor(mc, 8));
            float ec = (q < KCOMP) ? expf(cv - mc) : 0.0f;
            float scv = ec;
            scv += __shfl_xor(scv, 1); scv += __shfl_xor(scv, 2);
            scv += __shfl_xor(scv, 4); scv += __shfl_xor(scv, 8);
            float pc = (q >= 1 && q < KCOMP) ? ec / scv : -1.0f;
            int ci = q;
#pragma unroll
            for (int off = 1; off <= 8; off <<= 1) {
                float po = __shfl_xor(pc, off);
                int   io = __shfl_xor(ci, off);
                if (po > pc || (po == pc && io < ci)) { pc = po; ci = io; }
            }
            if (q == 0) { comp_s[n] = pc; comp_i[n] = (unsigned char)ci; }
        }
    }
    __syncthreads();

    // ================= Phase B2: per-class sort + decode + NMS ==============
    const float CLIPV = 4.135166556742356f; // log(1000/16)
    for (int rep = 0; rep < 5; ++rep) {
        int c  = 1 + wave + rep * 16;  // 1..80
        int cc = c - 1;
        int M = ccnt[c]; if (M > CAP) M = CAP;

        // ---- rank-sort (ties by ascending n == stable argsort) -------------
        int i1 = lane + 64;
        float s0 = (lane < M) ? cscore[cc][lane] : 0.0f;
        float s1 = (i1  < M) ? cscore[cc][i1]  : 0.0f;
        int   n0 = (lane < M) ? cnn[cc][lane] : 0;
        int   n1 = (i1  < M) ? cnn[cc][i1]  : 0;
        int r0 = 0, r1 = 0;
        for (int j = 0; j < M; ++j) {
            float sj = cscore[cc][j];     // LDS broadcast
            int   nj = cnn[cc][j];
            r0 += (int)((sj > s0) | ((sj == s0) & (nj < n0)));
            r1 += (int)((sj > s1) | ((sj == s1) & (nj < n1)));
        }
        if (lane < M) { sS[wave][r0] = s0; sN[wave][r0] = (unsigned short)n0; }
        if (i1  < M) { sS[wave][r1] = s1; sN[wave][r1] = (unsigned short)n1; }
        asm volatile("s_waitcnt lgkmcnt(0)" ::: "memory");  // wave-lockstep sync

        // ---- decode + clip the M sorted candidates -------------------------
#pragma unroll
        for (int k = 0; k < 2; ++k) {
            int p = lane + (k << 6);
            if (p < M) {
                int n = sN[wave][p];
                float4 r4 = ((const float4*)boxreg)[n * NCLS + c];
                float4 pp = ((const float4*)props)[n];
                float w  = pp.z - pp.x + 1.0f, h = pp.w - pp.y + 1.0f;
                float cx = pp.x + 0.5f * w,  cy = pp.y + 0.5f * h;
                float dx = r4.x / 10.0f, dy = r4.y / 10.0f;
                float dw = fminf(r4.z / 5.0f, CLIPV), dh = fminf(r4.w / 5.0f, CLIPV);
                float pcx = dx * w + cx, pcy = dy * h + cy;
                float pw = expf(dw) * w, ph = expf(dh) * h;
                float bx1 = fminf(fmaxf(pcx - 0.5f * pw, 0.0f), 1332.0f);
                float by1 = fminf(fmaxf(pcy - 0.5f * ph, 0.0f), 799.0f);
                float bx2 = fminf(fmaxf(pcx + 0.5f * pw - 1.0f, 0.0f), 1332.0f);
                float by2 = fminf(fmaxf(pcy + 0.5f * ph - 1.0f, 0.0f), 799.0f);
                wbox[wave][p] = make_float4(bx1, by1, bx2, by2);
            }
        }
        asm volatile("s_waitcnt lgkmcnt(0)" ::: "memory");

        // ---- greedy NMS (slot p -> lane p%64, bit p/64; proven R4 code) ----
        unsigned int keep = 0;
        if (lane < M) keep |= 1u;
        if (i1  < M) keep |= 2u;
        for (int i = 0; i < M; ++i) {
            unsigned int ki = __shfl(keep, i & 63);
            if (!((ki >> (i >> 6)) & 1u)) continue;
            float4 bi = wbox[wave][i];    // LDS broadcast
            float aarea = (bi.z - bi.x + 1.0f) * (bi.w - bi.y + 1.0f);
#pragma unroll
            for (int k = 0; k < 2; ++k) {
                int p = lane + (k << 6);
                if (((keep >> k) & 1u) && p > i && p < M) {
                    float4 bp = wbox[wave][p];
                    float barea = (bp.z - bp.x + 1.0f) * (bp.w - bp.y + 1.0f);
                    float lx = fmaxf(bi.x, bp.x), ly = fmaxf(bi.y, bp.y);
                    float rx = fminf(bi.z, bp.z), ry = fminf(bi.w, bp.w);
                    float iw = fmaxf(rx - lx + 1.0f, 0.0f);
                    float ih = fmaxf(ry - ly + 1.0f, 0.0f);
                    float inter = iw * ih;
                    float iou = inter / (aarea + barea - inter);
                    if (iou > 0.5f) keep &= ~(1u << k);
                }
            }
        }

        // ---- append survivors: key->LDS, box->ws (global) ------------------
#pragma unroll
        for (int k = 0; k < 2; ++k) {
            int p = lane + (k << 6);
            bool v = (p < M) && ((keep >> k) & 1u);
            unsigned long long bm = __ballot(v);
            int cm = __popcll(bm);
            int base = 0;
            if (lane == 0 && cm) base = atomicAdd(&candCnt, cm);
            base = __shfl(base, 0);
            if (v) {
                int idx = base + __popcll(bm & ((1ull << lane) - 1ull));
                if (idx < MAXK) {
                    // meta = (flat sorted index)<<10 | n  (reference tie-break)
                    unsigned int meta =
                        (unsigned int)(((cc * NPROP + p) << 10) | sN[wave][p]);
                    candKey[idx] =
                        ((unsigned long long)__float_as_uint(sS[wave][p]) << 32)
                        | (unsigned int)~meta;
                    ((float4*)ws)[idx] = wbox[wave][p];
                }
            }
        }
    }
    __syncthreads();

    // ================= Phase C: histogram-select top-100 ====================
    if (tid < 512) hist[tid] = 0;
    __syncthreads();
    int K = candCnt; if (K > MAXK) K = MAXK;

    // score in (0.05,1] -> (bits>>17) in [7846,8128]; bucket -7680 in [166,448]
    for (int j = tid; j < K; j += 1024) {
        int b = (int)(candKey[j] >> 49) - 7680;
        b = b < 0 ? 0 : (b > 511 ? 511 : b);
        atomicAdd(&hist[b], 1);
    }
    __syncthreads();
    if (wave == 0) {   // in-place suffix count S[b] = #keys in buckets > b
        int base = lane * 8;
        int tot = 0;
#pragma unroll
        for (int t = 0; t < 8; ++t) tot += hist[base + t];
        int sfx = tot;
        for (int off = 1; off < 64; off <<= 1) {
            int o = __shfl_down(sfx, off);
            if (lane + off < 64) sfx += o;
        }
        int run = sfx - tot;
        for (int t = 7; t >= 0; --t) {
            int h = hist[base + t];
            hist[base + t] = run;
            run += h;
        }
    }
    __syncthreads();
    for (int j = tid; j < K; j += 1024) {
        unsigned long long kj = candKey[j];
        int b = (int)(kj >> 49) - 7680;
        b = b < 0 ? 0 : (b > 511 ? 511 : b);
        if (hist[b] < DETS) {
            int pos = atomicAdd(&rcnt, 1);
            if (pos < RMAXR) { rkey[pos] = kj; ridx[pos] = j; }
        }
    }
    __syncthreads();
    int R = rcnt; if (R > RMAXR) R = RMAXR;

    if (tid < R) {
        unsigned long long ki = rkey[tid];
        int r = 0;
        for (int j = 0; j < R; ++j) r += (int)(rkey[j] > ki);
        if (r < DETS) {
            float4 b4 = ((const float4*)ws)[ridx[tid]];
            unsigned int meta = ~(unsigned int)(ki & 0xFFFFFFFFull);
            int n = meta & 1023;
            int flat = meta >> 10;
            out[r * 4 + 0] = b4.x;
            out[r * 4 + 1] = b4.y;
            out[r * 4 + 2] = b4.z;
            out[r * 4 + 3] = b4.w;
            out[400 + r] = __uint_as_float((unsigned int)(ki >> 32));
            out[500 + r] = comp_s[n];
            out[600 + r] = (float)(flat / NPROP + 1);
            out[700 + r] = (float)comp_i[n];
        }
    }
}

extern "C" void kernel_launch(void* const* d_in, const int* in_sizes, int n_in,
                              void* d_out, int out_size, void* d_ws, size_t ws_size,
                              hipStream_t stream)
{
    const float* cls  = (const float*)d_in[0];
    const float* comp = (const float*)d_in[1];
    const float* breg = (const float*)d_in[2];
    const float* prop = (const float*)d_in[3];

    hipLaunchKernelGGL(fused_kernel, dim3(1), dim3(1024), 0, stream,
                       cls, comp, breg, prop, (float*)d_ws, (float*)d_out, out_size);
}

// Round 7
// 61.685 us; speedup vs baseline: 1.8841x; 1.8841x over previous
//
#include <hip/hip_runtime.h>
#include <math.h>

#define NPROP 1000
#define NCLS  81
#define KCOMP 11
#define NFG   80
#define DETS  100
#define SLOTS 128     // fixed survivor slots per class (M observed ~<=50)
#define RMAXR 512

// ws layout (float indices):
//   counts: int[80] at [0..80)
//   slots:  [80][SLOTS][8] floats at 128: {key_lo, key_hi, x1, y1, x2, y2, 0, 0}
#define WS_COUNTS 0
#define WS_SLOTS  128

// K1: per-class NMS, self-contained (recomputes row softmax stats in-block).
// 80 blocks x 256 threads. No cross-block communication, no global atomics.
__global__ __launch_bounds__(256) void nms_kernel(
    const float* __restrict__ cls_logits,
    const float* __restrict__ boxreg,
    const float* __restrict__ props,
    float* __restrict__ ws)
{
    __shared__ float m_lds[NPROP];
    __shared__ float s_lds[NPROP];
    __shared__ float ls[SLOTS];
    __shared__ int   ln[SLOTS];
    __shared__ float ss[SLOTS];
    __shared__ int   sn[SLOTS];
    __shared__ float4 sb[SLOTS];
    __shared__ int   cM;

    int tid  = threadIdx.x;
    int cfg  = blockIdx.x;       // class c = cfg+1
    int c    = cfg + 1;
    int lane = tid & 63;
    int wave = tid >> 6;

    // ---- stats: 16-lane group per row, 4 rows in flight per group (ILP) ----
    {
        int q = tid & 15, G = tid >> 4;   // 16 groups of 16 lanes
        for (int it = 0; it < 16; ++it) {
            float mv[4], sv[4];
            int   nr[4];
#pragma unroll
            for (int u = 0; u < 4; ++u) {
                int n  = it * 64 + u * 16 + G;
                nr[u]  = n;
                int na = (n < NPROP) ? n : 0;
                const float* row = &cls_logits[na * NCLS];
                float v0 = row[q], v1 = row[q + 16], v2 = row[q + 32],
                      v3 = row[q + 48], v4 = row[q + 64];
                float v5 = (q == 0) ? row[80] : -INFINITY;
                float m = fmaxf(fmaxf(fmaxf(v0, v1), fmaxf(v2, v3)), fmaxf(v4, v5));
                m = fmaxf(m, __shfl_xor(m, 1));
                m = fmaxf(m, __shfl_xor(m, 2));
                m = fmaxf(m, __shfl_xor(m, 4));
                m = fmaxf(m, __shfl_xor(m, 8));
                float s = expf(v0 - m) + expf(v1 - m) + expf(v2 - m) +
                          expf(v3 - m) + expf(v4 - m) +
                          ((q == 0) ? expf(v5 - m) : 0.0f);
                s += __shfl_xor(s, 1);
                s += __shfl_xor(s, 2);
                s += __shfl_xor(s, 4);
                s += __shfl_xor(s, 8);
                mv[u] = m; sv[u] = s;
            }
#pragma unroll
            for (int u = 0; u < 4; ++u) {
                if (q == 0 && nr[u] < NPROP) { m_lds[nr[u]] = mv[u]; s_lds[nr[u]] = sv[u]; }
            }
        }
    }
    __syncthreads();

    // ---- compact valid entries (wave 0; preserves n-order) ----
    if (wave == 0) {
        float pv[16];
#pragma unroll
        for (int t = 0; t < 16; ++t) {
            int n = t * 64 + lane;
            pv[t] = (n < NPROP)
                  ? expf(cls_logits[n * NCLS + c] - m_lds[n]) / s_lds[n] : 0.0f;
        }
        int cnt = 0;
#pragma unroll
        for (int t = 0; t < 16; ++t) {
            int n = t * 64 + lane;
            bool v = (n < NPROP) && (pv[t] > 0.05f);
            unsigned long long bm = __ballot(v);
            if (v) {
                int pos = cnt + __popcll(bm & ((1ull << lane) - 1ull));
                if (pos < SLOTS) { ls[pos] = pv[t]; ln[pos] = n; }
            }
            cnt += __popcll(bm);
        }
        if (lane == 0) cM = (cnt > SLOTS) ? SLOTS : cnt;
    }
    __syncthreads();
    int M = cM;

    // ---- rank sort (block-wide; ties by compact idx == original n order) ----
    if (tid < M) {
        float si = ls[tid]; int ni = ln[tid];
        int r = 0;
        for (int j = 0; j < M; ++j) {
            float sj = ls[j]; int nj = ln[j];
            r += (int)((sj > si) | ((sj == si) & (nj < ni)));
        }
        ss[r] = si; sn[r] = ni;
    }
    __syncthreads();

    // ---- decode + clip (block-wide, one slot per thread) ----
    const float CLIPV = 4.135166556742356f; // log(1000/16)
    if (tid < M) {
        int n = sn[tid];
        float4 r4 = ((const float4*)boxreg)[n * NCLS + c];
        float4 pp = ((const float4*)props)[n];
        float w  = pp.z - pp.x + 1.0f, h = pp.w - pp.y + 1.0f;
        float cx = pp.x + 0.5f * w,  cy = pp.y + 0.5f * h;
        float dx = r4.x / 10.0f, dy = r4.y / 10.0f;
        float dw = fminf(r4.z / 5.0f, CLIPV), dh = fminf(r4.w / 5.0f, CLIPV);
        float pcx = dx * w + cx, pcy = dy * h + cy;
        float pw = expf(dw) * w, ph = expf(dh) * h;
        sb[tid] = make_float4(
            fminf(fmaxf(pcx - 0.5f * pw, 0.0f), 1332.0f),
            fminf(fmaxf(pcy - 0.5f * ph, 0.0f), 799.0f),
            fminf(fmaxf(pcx + 0.5f * pw - 1.0f, 0.0f), 1332.0f),
            fminf(fmaxf(pcy + 0.5f * ph - 1.0f, 0.0f), 799.0f));
    }
    __syncthreads();

    // ---- greedy NMS (wave 0; slot p -> lane p%64, bit p/64) + fixed-slot out --
    if (wave == 0) {
        unsigned int keep = 0;
        if (lane < M)      keep |= 1u;
        if (lane + 64 < M) keep |= 2u;
        for (int i = 0; i < M; ++i) {
            unsigned int ki = __shfl(keep, i & 63);
            if (!((ki >> (i >> 6)) & 1u)) continue;
            float4 bi = sb[i];   // LDS broadcast
            float aarea = (bi.z - bi.x + 1.0f) * (bi.w - bi.y + 1.0f);
#pragma unroll
            for (int k = 0; k < 2; ++k) {
                int p = lane + (k << 6);
                if (((keep >> k) & 1u) && p > i && p < M) {
                    float4 bp = sb[p];
                    float barea = (bp.z - bp.x + 1.0f) * (bp.w - bp.y + 1.0f);
                    float lx = fmaxf(bi.x, bp.x), ly = fmaxf(bi.y, bp.y);
                    float rx = fminf(bi.z, bp.z), ry = fminf(bi.w, bp.w);
                    float iw = fmaxf(rx - lx + 1.0f, 0.0f);
                    float ih = fmaxf(ry - ly + 1.0f, 0.0f);
                    float inter = iw * ih;
                    float iou = inter / (aarea + barea - inter);
                    if (iou > 0.5f) keep &= ~(1u << k);
                }
            }
        }
        int base = 0;
#pragma unroll
        for (int k = 0; k < 2; ++k) {
            int p = lane + (k << 6);
            bool v = (p < M) && ((keep >> k) & 1u);
            unsigned long long bm = __ballot(v);
            if (v) {
                int idx = base + __popcll(bm & ((1ull << lane) - 1ull));
                // meta = (flat sorted index)<<10 | n  (reference tie-break)
                unsigned int meta = (unsigned int)(((cfg * NPROP + p) << 10) | sn[p]);
                float4 b4 = sb[p];
                float* sp = &ws[WS_SLOTS + (cfg * SLOTS + idx) * 8];
                ((float4*)sp)[0] = make_float4(__uint_as_float(~meta), ss[p], b4.x, b4.y);
                ((float4*)sp)[1] = make_float4(b4.z, b4.w, 0.0f, 0.0f);
            }
            base += __popcll(bm);
        }
        if (lane == 0) ((int*)ws)[WS_COUNTS + cfg] = base;
    }
}

// K2: out-defaults + histogram-select top-100 + lazy component softmax.
__global__ __launch_bounds__(1024) void topk_kernel(
    const float* __restrict__ comp_logits,
    const float* __restrict__ ws,
    float* __restrict__ out, int out_size)
{
    __shared__ int cnt_l[NFG];
    __shared__ int hist[1024];
    __shared__ unsigned long long rkey[RMAXR];
    __shared__ int ridx[RMAXR];
    __shared__ int rcnt;

    int tid = threadIdx.x;
    if (tid < out_size) out[tid] = (tid >= 400 && tid < 500) ? -1.0f : 0.0f;
    if (tid < NFG) cnt_l[tid] = ((const int*)ws)[WS_COUNTS + tid];
    hist[tid] = 0;
    if (tid == 0) rcnt = 0;
    __syncthreads();

    // pass 1: load keys to REGISTERS (static 10-deep) + histogram valid ones.
    // score in (0.05,1] -> (bits>>16) in [15692,16256]; bucket -15360.
    unsigned long long kv[10];
#pragma unroll
    for (int t = 0; t < 10; ++t) {
        int idx = t * 1024 + tid;            // < 10240 == NFG*SLOTS
        int cc = idx >> 7, j = idx & (SLOTS - 1);
        kv[t] = (j < cnt_l[cc])
              ? *(const unsigned long long*)&ws[WS_SLOTS + idx * 8] : 0ull;
    }
#pragma unroll
    for (int t = 0; t < 10; ++t) {
        if (kv[t]) {
            int b = (int)((unsigned int)(kv[t] >> 48)) - 15360;
            b = b < 0 ? 0 : (b > 1023 ? 1023 : b);
            atomicAdd(&hist[b], 1);
        }
    }
    __syncthreads();

    // in-place suffix count S[b] = #keys in buckets > b (wave 0)
    if (tid < 64) {
        int base = tid * 16;
        int tot = 0;
#pragma unroll
        for (int t = 0; t < 16; ++t) tot += hist[base + t];
        int sfx = tot;
        for (int off = 1; off < 64; off <<= 1) {
            int o = __shfl_down(sfx, off);
            if (tid + off < 64) sfx += o;
        }
        int run = sfx - tot;
        for (int t = 15; t >= 0; --t) {
            int h = hist[base + t];
            hist[base + t] = run;
            run += h;
        }
    }
    __syncthreads();

    // pass 2: refine set from registers (no reload)
#pragma unroll
    for (int t = 0; t < 10; ++t) {
        if (kv[t]) {
            int b = (int)((unsigned int)(kv[t] >> 48)) - 15360;
            b = b < 0 ? 0 : (b > 1023 ? 1023 : b);
            if (hist[b] < DETS) {
                int pos = atomicAdd(&rcnt, 1);
                if (pos < RMAXR) { rkey[pos] = kv[t]; ridx[pos] = t * 1024 + tid; }
            }
        }
    }
    __syncthreads();
    int R = rcnt < RMAXR ? rcnt : RMAXR;

    // exact rank within refine set (== global rank by bucket monotonicity)
    if (tid < R) {
        unsigned long long ki = rkey[tid];
        int r = 0;
        for (int j = 0; j < R; ++j) r += (int)(rkey[j] > ki);
        if (r < DETS) {
            const float* sp = &ws[WS_SLOTS + ridx[tid] * 8];
            float4 a  = ((const float4*)sp)[0];
            float4 b2 = ((const float4*)sp)[1];
            unsigned int meta = ~__float_as_uint(a.x);
            int n = meta & 1023;
            int flat = meta >> 10;

            // lazy component softmax + fg argmax (first occurrence) for row n
            float y[KCOMP];
            float mc = -INFINITY;
#pragma unroll
            for (int k = 0; k < KCOMP; ++k) {
                y[k] = comp_logits[n * KCOMP + k];
                mc = fmaxf(mc, y[k]);
            }
            float sc = 0.0f;
#pragma unroll
            for (int k = 0; k < KCOMP; ++k) sc += expf(y[k] - mc);
            float best = -1.0f; int bi = 0;
#pragma unroll
            for (int k = 1; k < KCOMP; ++k) {
                float pk = expf(y[k] - mc) / sc;
                if (pk > best) { best = pk; bi = k; }
            }

            out[r * 4 + 0] = a.z;
            out[r * 4 + 1] = a.w;
            out[r * 4 + 2] = b2.x;
            out[r * 4 + 3] = b2.y;
            out[400 + r] = a.y;
            out[500 + r] = best;
            out[600 + r] = (float)(flat / NPROP + 1);
            out[700 + r] = (float)bi;
        }
    }
}

extern "C" void kernel_launch(void* const* d_in, const int* in_sizes, int n_in,
                              void* d_out, int out_size, void* d_ws, size_t ws_size,
                              hipStream_t stream)
{
    const float* cls  = (const float*)d_in[0];
    const float* comp = (const float*)d_in[1];
    const float* breg = (const float*)d_in[2];
    const float* prop = (const float*)d_in[3];
    float* ws  = (float*)d_ws;
    float* out = (float*)d_out;

    hipLaunchKernelGGL(nms_kernel, dim3(NFG), dim3(256), 0, stream,
                       cls, breg, prop, ws);
    hipLaunchKernelGGL(topk_kernel, dim3(1), dim3(1024), 0, stream,
                       comp, ws, out, out_size);
}

// Round 8
// 30.922 us; speedup vs baseline: 3.7585x; 1.9948x over previous
//
#include <hip/hip_runtime.h>
#include <math.h>

#define NPROP 1000
#define NCLS  81
#define KCOMP 11
#define NFG   80
#define DETS  100
#define SLOTS 128
#define RMAXR 512

// ws layout (float indices)
#define WS_PROBS  0        // [80][1000] class-major fg probs
#define WS_COUNTS 80000    // int[80] per-class survivor count
#define WS_SLOTS  80128    // [80][SLOTS][8]: {~meta, score, x1,y1, x2,y2, 0,0}

// K1: row softmax -> transposed prob write. 250 blocks x 256 (1 row per wave).
__global__ __launch_bounds__(256) void prep_kernel(
    const float* __restrict__ cls_logits,
    float* __restrict__ ws,
    float* __restrict__ out, int out_size)
{
    int tid = threadIdx.x, bid = blockIdx.x;
    int lane = tid & 63, wave = tid >> 6;

    // output defaults (padded slots): score slots -1, everything else 0
    if (bid < 4) {
        int oi = bid * 256 + tid;
        if (oi < out_size) out[oi] = (oi >= 400 && oi < 500) ? -1.0f : 0.0f;
    }

    int n = bid * 4 + wave;
    if (n >= NPROP) return;

    float x0 = cls_logits[n * NCLS + lane];
    float x1 = (lane < NCLS - 64) ? cls_logits[n * NCLS + 64 + lane] : -INFINITY;
    float m = fmaxf(x0, x1);
    for (int off = 32; off; off >>= 1) m = fmaxf(m, __shfl_xor(m, off));
    float e0 = expf(x0 - m);
    float e1 = (lane < NCLS - 64) ? expf(x1 - m) : 0.0f;
    float s = e0 + e1;
    for (int off = 32; off; off >>= 1) s += __shfl_xor(s, off);
    if (lane >= 1)        ws[WS_PROBS + (lane - 1) * NPROP + n] = e0 / s;  // c=1..63
    if (lane < NCLS - 64) ws[WS_PROBS + (lane + 63) * NPROP + n] = e1 / s; // c=64..80
}

// K2: per-class compact (contiguous prob reads) -> sort -> decode -> NMS
//     -> fixed-slot survivors. 80 blocks x 64 threads.
__global__ __launch_bounds__(64) void nms_kernel(
    const float* __restrict__ boxreg,
    const float* __restrict__ props,
    float* __restrict__ ws)
{
    __shared__ float  ls[SLOTS];
    __shared__ int    ln[SLOTS];
    __shared__ float  ss[SLOTS];
    __shared__ int    sn[SLOTS];
    __shared__ float4 sb[SLOTS];

    int cfg  = blockIdx.x;   // class c = cfg + 1
    int c    = cfg + 1;
    int lane = threadIdx.x;
    const float* probs = &ws[WS_PROBS + cfg * NPROP];

    // ---- 16 coalesced, independent prob loads (all in flight) ----
    float pv[16];
#pragma unroll
    for (int t = 0; t < 16; ++t) {
        int n = t * 64 + lane;
        pv[t] = (n < NPROP) ? probs[n] : 0.0f;
    }

    // ---- compact valid entries (preserves original n-order) ----
    int cnt = 0;
#pragma unroll
    for (int t = 0; t < 16; ++t) {
        int n = t * 64 + lane;
        bool v = (n < NPROP) && (pv[t] > 0.05f);
        unsigned long long bm = __ballot(v);
        if (v) {
            int pos = cnt + __popcll(bm & ((1ull << lane) - 1ull));
            if (pos < SLOTS) { ls[pos] = pv[t]; ln[pos] = n; }
        }
        cnt += __popcll(bm);
    }
    int M = (cnt > SLOTS) ? SLOTS : cnt;
    __syncthreads();

    // ---- rank sort (descending score, ties by compact idx == n order) ----
    for (int i = lane; i < M; i += 64) {
        float si = ls[i];
        int r = 0;
        for (int j = 0; j < M; ++j) {
            float sj = ls[j];
            r += (int)((sj > si) | ((sj == si) & (j < i)));
        }
        ss[r] = si; sn[r] = ln[i];
    }
    __syncthreads();

    // ---- decode + clip the M sorted candidates ----
    const float CLIPV = 4.135166556742356f; // log(1000/16)
    for (int p = lane; p < M; p += 64) {
        int n = sn[p];
        float4 r4 = ((const float4*)boxreg)[n * NCLS + c];
        float4 pp = ((const float4*)props)[n];
        float w  = pp.z - pp.x + 1.0f, h = pp.w - pp.y + 1.0f;
        float cx = pp.x + 0.5f * w,  cy = pp.y + 0.5f * h;
        float dx = r4.x / 10.0f, dy = r4.y / 10.0f;
        float dw = fminf(r4.z / 5.0f, CLIPV), dh = fminf(r4.w / 5.0f, CLIPV);
        float pcx = dx * w + cx, pcy = dy * h + cy;
        float pw = expf(dw) * w, ph = expf(dh) * h;
        sb[p] = make_float4(
            fminf(fmaxf(pcx - 0.5f * pw, 0.0f), 1332.0f),
            fminf(fmaxf(pcy - 0.5f * ph, 0.0f), 799.0f),
            fminf(fmaxf(pcx + 0.5f * pw - 1.0f, 0.0f), 1332.0f),
            fminf(fmaxf(pcy + 0.5f * ph - 1.0f, 0.0f), 799.0f));
    }
    __syncthreads();

    // ---- greedy NMS: slot p -> lane p%64, bit p/64 ----
    unsigned int keep = 0;
    if (lane < M)      keep |= 1u;
    if (lane + 64 < M) keep |= 2u;
    for (int i = 0; i < M; ++i) {
        unsigned int ki = __shfl(keep, i & 63);
        if (!((ki >> (i >> 6)) & 1u)) continue;
        float4 bi = sb[i];   // LDS broadcast
        float aarea = (bi.z - bi.x + 1.0f) * (bi.w - bi.y + 1.0f);
#pragma unroll
        for (int k = 0; k < 2; ++k) {
            int p = lane + (k << 6);
            if (((keep >> k) & 1u) && p > i && p < M) {
                float4 bp = sb[p];
                float barea = (bp.z - bp.x + 1.0f) * (bp.w - bp.y + 1.0f);
                float lx = fmaxf(bi.x, bp.x), ly = fmaxf(bi.y, bp.y);
                float rx = fminf(bi.z, bp.z), ry = fminf(bi.w, bp.w);
                float iw = fmaxf(rx - lx + 1.0f, 0.0f);
                float ih = fmaxf(ry - ly + 1.0f, 0.0f);
                float inter = iw * ih;
                float iou = inter / (aarea + barea - inter);
                if (iou > 0.5f) keep &= ~(1u << k);
            }
        }
    }

    // ---- survivors to fixed per-class slots (no global atomics) ----
    int base = 0;
#pragma unroll
    for (int k = 0; k < 2; ++k) {
        int p = lane + (k << 6);
        bool v = (p < M) && ((keep >> k) & 1u);
        unsigned long long bm = __ballot(v);
        if (v) {
            int idx = base + __popcll(bm & ((1ull << lane) - 1ull));
            // meta = (flat sorted index)<<10 | n  (reference tie-break)
            unsigned int meta = (unsigned int)(((cfg * NPROP + p) << 10) | sn[p]);
            float4 b4 = sb[p];
            float* sp = &ws[WS_SLOTS + (cfg * SLOTS + idx) * 8];
            ((float4*)sp)[0] = make_float4(__uint_as_float(~meta), ss[p], b4.x, b4.y);
            ((float4*)sp)[1] = make_float4(b4.z, b4.w, 0.0f, 0.0f);
        }
        base += __popcll(bm);
    }
    if (lane == 0) ((int*)ws)[WS_COUNTS + cfg] = base;
}

// K3: histogram-select top-100 + lazy component softmax. 1 block x 1024.
__global__ __launch_bounds__(1024) void topk_kernel(
    const float* __restrict__ comp_logits,
    const float* __restrict__ ws,
    float* __restrict__ out)
{
    __shared__ int cnt_l[NFG];
    __shared__ int hist[1024];
    __shared__ unsigned long long rkey[RMAXR];
    __shared__ int ridx[RMAXR];
    __shared__ int rcnt;

    int tid = threadIdx.x;
    if (tid < NFG) cnt_l[tid] = ((const int*)ws)[WS_COUNTS + tid];
    hist[tid] = 0;
    if (tid == 0) rcnt = 0;
    __syncthreads();

    // pass 1: keys to REGISTERS (static 10-deep) + histogram valid ones.
    // score in (0.05,1] -> (bits>>16) in [15692,16256]; bucket -15360.
    unsigned long long kv[10];
#pragma unroll
    for (int t = 0; t < 10; ++t) {
        int idx = t * 1024 + tid;            // < 10240 == NFG*SLOTS
        int cc = idx >> 7, j = idx & (SLOTS - 1);
        kv[t] = (j < cnt_l[cc])
              ? *(const unsigned long long*)&ws[WS_SLOTS + idx * 8] : 0ull;
    }
#pragma unroll
    for (int t = 0; t < 10; ++t) {
        if (kv[t]) {
            int b = (int)((unsigned int)(kv[t] >> 48)) - 15360;
            b = b < 0 ? 0 : (b > 1023 ? 1023 : b);
            atomicAdd(&hist[b], 1);
        }
    }
    __syncthreads();

    // in-place suffix count S[b] = #keys in buckets > b (wave 0)
    if (tid < 64) {
        int base = tid * 16;
        int tot = 0;
#pragma unroll
        for (int t = 0; t < 16; ++t) tot += hist[base + t];
        int sfx = tot;
        for (int off = 1; off < 64; off <<= 1) {
            int o = __shfl_down(sfx, off);
            if (tid + off < 64) sfx += o;
        }
        int run = sfx - tot;
        for (int t = 15; t >= 0; --t) {
            int h = hist[base + t];
            hist[base + t] = run;
            run += h;
        }
    }
    __syncthreads();

    // pass 2: refine set from registers (no reload)
#pragma unroll
    for (int t = 0; t < 10; ++t) {
        if (kv[t]) {
            int b = (int)((unsigned int)(kv[t] >> 48)) - 15360;
            b = b < 0 ? 0 : (b > 1023 ? 1023 : b);
            if (hist[b] < DETS) {
                int pos = atomicAdd(&rcnt, 1);
                if (pos < RMAXR) { rkey[pos] = kv[t]; ridx[pos] = t * 1024 + tid; }
            }
        }
    }
    __syncthreads();
    int R = rcnt < RMAXR ? rcnt : RMAXR;

    // exact rank within refine set (== global rank by bucket monotonicity)
    if (tid < R) {
        unsigned long long ki = rkey[tid];
        int r = 0;
        for (int j = 0; j < R; ++j) r += (int)(rkey[j] > ki);
        if (r < DETS) {
            const float* sp = &ws[WS_SLOTS + ridx[tid] * 8];
            float4 a  = ((const float4*)sp)[0];
            float4 b2 = ((const float4*)sp)[1];
            unsigned int meta = ~__float_as_uint(a.x);
            int n = meta & 1023;
            int flat = meta >> 10;

            // lazy component softmax + fg argmax (first occurrence) for row n
            float y[KCOMP];
            float mc = -INFINITY;
#pragma unroll
            for (int k = 0; k < KCOMP; ++k) {
                y[k] = comp_logits[n * KCOMP + k];
                mc = fmaxf(mc, y[k]);
            }
            float sc = 0.0f;
#pragma unroll
            for (int k = 0; k < KCOMP; ++k) sc += expf(y[k] - mc);
            float best = -1.0f; int bi = 0;
#pragma unroll
            for (int k = 1; k < KCOMP; ++k) {
                float pk = expf(y[k] - mc) / sc;
                if (pk > best) { best = pk; bi = k; }
            }

            out[r * 4 + 0] = a.z;
            out[r * 4 + 1] = a.w;
            out[r * 4 + 2] = b2.x;
            out[r * 4 + 3] = b2.y;
            out[400 + r] = a.y;
            out[500 + r] = best;
            out[600 + r] = (float)(flat / NPROP + 1);
            out[700 + r] = (float)bi;
        }
    }
}

extern "C" void kernel_launch(void* const* d_in, const int* in_sizes, int n_in,
                              void* d_out, int out_size, void* d_ws, size_t ws_size,
                              hipStream_t stream)
{
    const float* cls  = (const float*)d_in[0];
    const float* comp = (const float*)d_in[1];
    const float* breg = (const float*)d_in[2];
    const float* prop = (const float*)d_in[3];
    float* ws  = (float*)d_ws;
    float* out = (float*)d_out;

    hipLaunchKernelGGL(prep_kernel, dim3(250), dim3(256), 0, stream,
                       cls, ws, out, out_size);
    hipLaunchKernelGGL(nms_kernel, dim3(NFG), dim3(64), 0, stream,
                       breg, prop, ws);
    hipLaunchKernelGGL(topk_kernel, dim3(1), dim3(1024), 0, stream,
                       comp, ws, out);
}